// Round 1
// baseline (394229.810 us; speedup 1.0000x reference)
//
#include <hip/hip_runtime.h>
#include <hip/hip_cooperative_groups.h>
#include <hip/hip_bf16.h>

// Problem constants (B=2, S=1024, I=1024, H=1024, L=2)
constexpr int HD  = 1024;   // hidden size == input size
constexpr int SEQ = 2048;   // B*S flattened steps per layer
constexpr int NL  = 2;      // layers
constexpr int NWG = 256;    // workgroups in cooperative kernel (1 per CU)
constexpr int TPB = 256;    // threads per block
constexpr int RPW = HD / NWG; // rows of r/z/hh owned per WG = 4

// ---------------------------------------------------------------------------
// Phase A: Ax[gl][t][row] = X[t,:] . W_g[l][row, HD:2HD] + b_g[l][row]
// gl = l*3 + g, g in {0:r, 1:z, 2:h}. Classic 64x64 fp32 LDS-tiled GEMM.
// ---------------------------------------------------------------------------
__global__ void __launch_bounds__(256) ax_gemm_kernel(
    const float* __restrict__ X,
    const float* __restrict__ Wr, const float* __restrict__ Wz, const float* __restrict__ Wh,
    const float* __restrict__ br, const float* __restrict__ bz, const float* __restrict__ bh,
    float* __restrict__ ax)
{
  __shared__ float sX[16][64];   // [k][t]
  __shared__ float sW[16][64];   // [k][row]

  const int gl = blockIdx.z, l = gl / 3, g = gl % 3;
  const float* W    = (g == 0 ? Wr : (g == 1 ? Wz : Wh)) + (size_t)l * HD * (2 * HD) + HD;
  const float* bias = (g == 0 ? br : (g == 1 ? bz : bh)) + l * HD;
  const int t0 = blockIdx.y * 64, r0 = blockIdx.x * 64;
  const int tid = threadIdx.x;
  const int tx = tid & 15;        // row micro-tile index
  const int ty = tid >> 4;        // t  micro-tile index
  const int lt = tid >> 2;        // staging local row 0..63
  const int lk = (tid & 3) * 4;   // staging k offset {0,4,8,12}

  float acc[4][4] = {};           // [i: t][j: row]

  for (int k0 = 0; k0 < HD; k0 += 16) {
    float4 xv = *reinterpret_cast<const float4*>(&X[(size_t)(t0 + lt) * HD + k0 + lk]);
    float4 wv = *reinterpret_cast<const float4*>(&W[(size_t)(r0 + lt) * (2 * HD) + k0 + lk]);
    __syncthreads();
    sX[lk + 0][lt] = xv.x; sX[lk + 1][lt] = xv.y; sX[lk + 2][lt] = xv.z; sX[lk + 3][lt] = xv.w;
    sW[lk + 0][lt] = wv.x; sW[lk + 1][lt] = wv.y; sW[lk + 2][lt] = wv.z; sW[lk + 3][lt] = wv.w;
    __syncthreads();
#pragma unroll
    for (int k = 0; k < 16; ++k) {
      float4 a = *reinterpret_cast<const float4*>(&sX[k][ty * 4]);
      float4 b = *reinterpret_cast<const float4*>(&sW[k][tx * 4]);
      const float av[4] = {a.x, a.y, a.z, a.w};
      const float bv[4] = {b.x, b.y, b.z, b.w};
#pragma unroll
      for (int i = 0; i < 4; ++i)
#pragma unroll
        for (int j = 0; j < 4; ++j)
          acc[i][j] += av[i] * bv[j];
    }
  }

  float4 bb = *reinterpret_cast<const float4*>(&bias[r0 + tx * 4]);
  const float bv[4] = {bb.x, bb.y, bb.z, bb.w};
#pragma unroll
  for (int i = 0; i < 4; ++i) {
    float4 o;
    o.x = acc[i][0] + bv[0]; o.y = acc[i][1] + bv[1];
    o.z = acc[i][2] + bv[2]; o.w = acc[i][3] + bv[3];
    *reinterpret_cast<float4*>(
        &ax[((size_t)gl * SEQ + t0 + ty * 4 + i) * HD + r0 + tx * 4]) = o;
  }
}

// ---------------------------------------------------------------------------
// Phase B: the serial 4096-step scan. Persistent cooperative kernel.
// WG b owns rows [4b, 4b+4) of r, z and hh. All h-part weight rows for both
// layers live in LDS (96 KB). Two grid syncs per step.
// ---------------------------------------------------------------------------
__global__ void __launch_bounds__(TPB) gru_seq_kernel(
    const float* __restrict__ Wr, const float* __restrict__ Wz, const float* __restrict__ Wh,
    const float* __restrict__ ax,
    float* __restrict__ hbuf, float* __restrict__ rhbuf, float* __restrict__ outp)
{
  __shared__ float sW[NL][3][RPW][HD];  // 96 KB: h-part weight rows
  __shared__ float sVec[HD];            // staged h (phase 1) / r*h (phase 2)
  __shared__ float sZ[RPW];
  __shared__ float sHold[RPW];

  const int wg = blockIdx.x;
  const int tid = threadIdx.x;
  const int row0 = wg * RPW;

  // Stage weights once: h-part = columns [0, HD) of W_g[l][row]
  for (int f = tid; f < NL * 3 * RPW * HD; f += TPB) {
    const int k  = f & (HD - 1);
    const int rr = f >> 10;          // 0..23
    const int r  = rr & 3;
    const int g  = (rr >> 2) % 3;
    const int l  = (rr >> 2) / 3;
    const float* W = (g == 0 ? Wr : (g == 1 ? Wz : Wh));
    sW[l][g][r][k] = W[((size_t)l * HD + row0 + r) * (2 * HD) + k];
  }
  if (tid < RPW) hbuf[row0 + tid] = 0.0f;   // h0 = 0
  __threadfence();

  cooperative_groups::grid_group grid = cooperative_groups::this_grid();
  grid.sync();

  for (int l = 0; l < NL; ++l) {
    for (int t = 0; t < SEQ; ++t) {
      // ---- phase 1: r, z rows; publish r*h -------------------------------
      for (int i = tid; i < HD; i += TPB) sVec[i] = hbuf[i];
      __syncthreads();
      {
        const int task = tid >> 5;       // 0..7 (0-3: r rows, 4-7: z rows)
        const int lane = tid & 31;
        const int g = task >> 2;         // 0=r, 1=z
        const int r = task & 3;
        const float* wrow = sW[l][g][r];
        float sum = 0.0f;
#pragma unroll 8
        for (int k = lane; k < HD; k += 32) sum += wrow[k] * sVec[k];
#pragma unroll
        for (int off = 16; off; off >>= 1) sum += __shfl_down(sum, off, 32);
        if (lane == 0) {
          const int row = row0 + r;
          const float pre = sum + ax[(((size_t)l * 3 + g) * SEQ + t) * HD + row];
          const float v = 1.0f / (1.0f + expf(-pre));
          if (g == 0) rhbuf[row] = v * sVec[row];       // r*h
          else { sZ[r] = v; sHold[r] = sVec[row]; }     // z, old h
        }
      }
      __threadfence();
      grid.sync();

      // ---- phase 2: hh rows; local h update ------------------------------
      for (int i = tid; i < HD; i += TPB) sVec[i] = rhbuf[i];
      __syncthreads();
      {
        const int task = tid >> 6;       // 0..3 (hh rows), 64 lanes each
        const int lane = tid & 63;
        const float* wrow = sW[l][2][task];
        float sum = 0.0f;
#pragma unroll 8
        for (int k = lane; k < HD; k += 64) sum += wrow[k] * sVec[k];
#pragma unroll
        for (int off = 32; off; off >>= 1) sum += __shfl_down(sum, off);
        if (lane == 0) {
          const int row = row0 + task;
          const float pre = sum + ax[(((size_t)l * 3 + 2) * SEQ + t) * HD + row];
          const float hh = tanhf(pre);
          const float z = sZ[task];
          hbuf[row] = (1.0f - z) * sHold[task] + z * hh;
        }
      }
      __threadfence();
      grid.sync();
    }
  }

  // (output, hidden) are identical: write h twice
  if (tid < RPW) {
    const float v = hbuf[row0 + tid];
    outp[row0 + tid] = v;
    outp[HD + row0 + tid] = v;
  }
}

// ---------------------------------------------------------------------------
extern "C" void kernel_launch(void* const* d_in, const int* in_sizes, int n_in,
                              void* d_out, int out_size, void* d_ws, size_t ws_size,
                              hipStream_t stream) {
  const float* emb = (const float*)d_in[0];
  const float* Wr  = (const float*)d_in[1];
  const float* br  = (const float*)d_in[2];
  const float* Wz  = (const float*)d_in[3];
  const float* bz  = (const float*)d_in[4];
  const float* Wh  = (const float*)d_in[5];
  const float* bh  = (const float*)d_in[6];
  float* outp = (float*)d_out;

  float* ws    = (float*)d_ws;
  float* ax    = ws;                                  // 6*SEQ*HD fp32 = 50.3 MB
  float* hbuf  = ws + (size_t)6 * SEQ * HD;           // HD fp32
  float* rhbuf = hbuf + HD;                           // HD fp32

  // Phase A: x-part contributions + bias, all gates/layers (parallel GEMM)
  dim3 g1(HD / 64, SEQ / 64, 6);
  ax_gemm_kernel<<<g1, 256, 0, stream>>>(emb, Wr, Wz, Wh, br, bz, bh, ax);

  // Phase B: serial scan, cooperative launch (grid-wide sync)
  void* args[] = {(void*)&Wr, (void*)&Wz, (void*)&Wh, (void*)&ax,
                  (void*)&hbuf, (void*)&rhbuf, (void*)&outp};
  hipLaunchCooperativeKernel((const void*)gru_seq_kernel, dim3(NWG), dim3(TPB),
                             args, 0, stream);
}

// Round 2
// 289403.149 us; speedup vs baseline: 1.3622x; 1.3622x over previous
//
#include <hip/hip_runtime.h>
#include <hip/hip_cooperative_groups.h>

// Problem constants (B=2, S=1024, I=1024, H=1024, L=2)
constexpr int HD    = 1024;       // hidden size == input size
constexpr int SEQ   = 2048;       // B*S flattened steps per layer
constexpr int NL    = 2;          // layers
constexpr int NSTEP = NL * SEQ;   // 4096 serial steps
constexpr int NWG   = 256;        // workgroups (1 per CU)
constexpr int TPB   = 256;        // threads per block
constexpr int RPW   = HD / NWG;   // rows owned per WG = 4

// ---------------------------------------------------------------------------
// device-scope (cross-XCD coherent) scalar load/store helpers
// ---------------------------------------------------------------------------
__device__ __forceinline__ float agload(const float* p) {
  return __hip_atomic_load(p, __ATOMIC_RELAXED, __HIP_MEMORY_SCOPE_AGENT);
}
__device__ __forceinline__ void agstore(float* p, float v) {
  __hip_atomic_store(p, v, __ATOMIC_RELAXED, __HIP_MEMORY_SCOPE_AGENT);
}

// ---------------------------------------------------------------------------
// Custom grid barrier: per-WG flag (uncontended) + master-poll (WG 0) + gen.
// ~1us vs ~54us for cooperative grid.sync. flags/gen zeroed by memset before
// launch; ph is a monotonically increasing phase id starting at 1.
// ---------------------------------------------------------------------------
__device__ __forceinline__ void gbarrier(int ph, int wg, int tid,
                                         int* flags, int* gen) {
  __threadfence();       // drain this thread's global writes (device scope)
  __syncthreads();       // all lanes of this WG done + fenced
  if (tid == 0)
    __hip_atomic_store(&flags[wg], ph, __ATOMIC_RELEASE, __HIP_MEMORY_SCOPE_AGENT);
  if (wg == 0) {
    // 256 threads each poll one WG's flag — fully parallel detection
    while (__hip_atomic_load(&flags[tid], __ATOMIC_ACQUIRE,
                             __HIP_MEMORY_SCOPE_AGENT) < ph) {}
    __syncthreads();
    if (tid == 0)
      __hip_atomic_store(gen, ph, __ATOMIC_RELEASE, __HIP_MEMORY_SCOPE_AGENT);
  }
  if (tid == 0) {
    while (__hip_atomic_load(gen, __ATOMIC_ACQUIRE,
                             __HIP_MEMORY_SCOPE_AGENT) < ph) {}
  }
  __syncthreads();
}

// ---------------------------------------------------------------------------
// Phase A: Ax[gl][t][row] = X[t,:] . W_g[l][row, HD:2HD] + b_g[l][row]
// gl = l*3 + g, g in {0:r, 1:z, 2:h}. 64x64 fp32 LDS-tiled GEMM (unchanged).
// ---------------------------------------------------------------------------
__global__ void __launch_bounds__(256) ax_gemm_kernel(
    const float* __restrict__ X,
    const float* __restrict__ Wr, const float* __restrict__ Wz, const float* __restrict__ Wh,
    const float* __restrict__ br, const float* __restrict__ bz, const float* __restrict__ bh,
    float* __restrict__ ax)
{
  __shared__ float sX[16][64];   // [k][t]
  __shared__ float sW[16][64];   // [k][row]

  const int gl = blockIdx.z, l = gl / 3, g = gl % 3;
  const float* W    = (g == 0 ? Wr : (g == 1 ? Wz : Wh)) + (size_t)l * HD * (2 * HD) + HD;
  const float* bias = (g == 0 ? br : (g == 1 ? bz : bh)) + l * HD;
  const int t0 = blockIdx.y * 64, r0 = blockIdx.x * 64;
  const int tid = threadIdx.x;
  const int tx = tid & 15;        // row micro-tile index
  const int ty = tid >> 4;        // t  micro-tile index
  const int lt = tid >> 2;        // staging local row 0..63
  const int lk = (tid & 3) * 4;   // staging k offset {0,4,8,12}

  float acc[4][4] = {};           // [i: t][j: row]

  for (int k0 = 0; k0 < HD; k0 += 16) {
    float4 xv = *reinterpret_cast<const float4*>(&X[(size_t)(t0 + lt) * HD + k0 + lk]);
    float4 wv = *reinterpret_cast<const float4*>(&W[(size_t)(r0 + lt) * (2 * HD) + k0 + lk]);
    __syncthreads();
    sX[lk + 0][lt] = xv.x; sX[lk + 1][lt] = xv.y; sX[lk + 2][lt] = xv.z; sX[lk + 3][lt] = xv.w;
    sW[lk + 0][lt] = wv.x; sW[lk + 1][lt] = wv.y; sW[lk + 2][lt] = wv.z; sW[lk + 3][lt] = wv.w;
    __syncthreads();
#pragma unroll
    for (int k = 0; k < 16; ++k) {
      float4 a = *reinterpret_cast<const float4*>(&sX[k][ty * 4]);
      float4 b = *reinterpret_cast<const float4*>(&sW[k][tx * 4]);
      const float av[4] = {a.x, a.y, a.z, a.w};
      const float bv[4] = {b.x, b.y, b.z, b.w};
#pragma unroll
      for (int i = 0; i < 4; ++i)
#pragma unroll
        for (int j = 0; j < 4; ++j)
          acc[i][j] += av[i] * bv[j];
    }
  }

  float4 bb = *reinterpret_cast<const float4*>(&bias[r0 + tx * 4]);
  const float bv[4] = {bb.x, bb.y, bb.z, bb.w};
#pragma unroll
  for (int i = 0; i < 4; ++i) {
    float4 o;
    o.x = acc[i][0] + bv[0]; o.y = acc[i][1] + bv[1];
    o.z = acc[i][2] + bv[2]; o.w = acc[i][3] + bv[3];
    *reinterpret_cast<float4*>(
        &ax[((size_t)gl * SEQ + t0 + ty * 4 + i) * HD + r0 + tx * 4]) = o;
  }
}

// ---------------------------------------------------------------------------
// Phase B: 4096-step serial scan. WG b owns rows [4b,4b+4) of r/z/hh.
// h-part weights (96 KB fp32) live in LDS. Two custom barriers per step.
// ax values for each phase are prefetched one phase ahead (latency hidden).
// ---------------------------------------------------------------------------
__global__ void __launch_bounds__(TPB) gru_seq_kernel(
    const float* __restrict__ Wr, const float* __restrict__ Wz, const float* __restrict__ Wh,
    const float* __restrict__ ax,
    float* __restrict__ hbuf, float* __restrict__ rhbuf,
    int* __restrict__ flags, int* __restrict__ gen,
    float* __restrict__ outp)
{
  __shared__ float sW[NL][3][RPW][HD];  // 96 KB: h-part weight rows
  __shared__ float sVec[HD];            // staged h (phase 1) / r*h (phase 2)
  __shared__ float sAxRZ[2 * RPW];      // ax for r,z rows, current step
  __shared__ float sAxH[RPW];           // ax for hh rows, current step
  __shared__ float sZ[RPW];
  __shared__ float sHold[RPW];

  const int wg = blockIdx.x;
  const int tid = threadIdx.x;
  const int row0 = wg * RPW;

  // Stage weights once: h-part = columns [0, HD) of W_g[l][row]
  for (int f = tid; f < NL * 3 * RPW * HD; f += TPB) {
    const int k  = f & (HD - 1);
    const int rr = f >> 10;          // 0..23
    const int r  = rr & 3;
    const int g  = (rr >> 2) % 3;
    const int l  = (rr >> 2) / 3;
    const float* W = (g == 0 ? Wr : (g == 1 ? Wz : Wh));
    sW[l][g][r][k] = W[((size_t)l * HD + row0 + r) * (2 * HD) + k];
  }
  __syncthreads();

  // Prologue: prefetch ax_r / ax_z for step 0 (consumed in first phase 1)
  float4 nax_r, nax_z, axh;
  if (tid == 0) {
    nax_r = *reinterpret_cast<const float4*>(&ax[(size_t)0 * SEQ * HD + row0]);
    nax_z = *reinterpret_cast<const float4*>(&ax[(size_t)1 * SEQ * HD + row0]);
  }

  int ph = 0;
  for (int u = 0; u < NSTEP; ++u) {
    const int l = u >> 11;           // layer
    const int t = u & (SEQ - 1);     // step within layer

    // ---- phase 1: r, z rows; publish r*h -------------------------------
    float hv[4];
#pragma unroll
    for (int q = 0; q < 4; ++q) hv[q] = agload(&hbuf[tid * 4 + q]);
    if (tid == 0) {
      // issue ax_h load for THIS step (consumed next phase — latency hidden)
      axh = *reinterpret_cast<const float4*>(
          &ax[(((size_t)l * 3 + 2) * SEQ + t) * HD + row0]);
      // publish the r/z ax values prefetched during the previous phase
      sAxRZ[0] = nax_r.x; sAxRZ[1] = nax_r.y; sAxRZ[2] = nax_r.z; sAxRZ[3] = nax_r.w;
      sAxRZ[4] = nax_z.x; sAxRZ[5] = nax_z.y; sAxRZ[6] = nax_z.z; sAxRZ[7] = nax_z.w;
    }
#pragma unroll
    for (int q = 0; q < 4; ++q) sVec[tid * 4 + q] = hv[q];
    __syncthreads();
    {
      const int task = tid >> 5;       // 0..7 (0-3: r rows, 4-7: z rows)
      const int lane = tid & 31;
      const int g = task >> 2;         // 0=r, 1=z
      const int r = task & 3;
      const float* wrow = sW[l][g][r];
      float sum = 0.0f;
#pragma unroll 8
      for (int k = lane; k < HD; k += 32) sum += wrow[k] * sVec[k];
#pragma unroll
      for (int off = 16; off; off >>= 1) sum += __shfl_down(sum, off, 32);
      if (lane == 0) {
        const float pre = sum + sAxRZ[g * 4 + r];
        const float v = 1.0f / (1.0f + expf(-pre));
        if (g == 0) agstore(&rhbuf[row0 + r], v * sVec[row0 + r]);   // r*h
        else { sZ[r] = v; sHold[r] = sVec[row0 + r]; }               // z, old h
      }
    }
    gbarrier(++ph, wg, tid, flags, gen);

    // ---- phase 2: hh rows; local h update ------------------------------
    float rv[4];
#pragma unroll
    for (int q = 0; q < 4; ++q) rv[q] = agload(&rhbuf[tid * 4 + q]);
    if (tid == 0) {
      sAxH[0] = axh.x; sAxH[1] = axh.y; sAxH[2] = axh.z; sAxH[3] = axh.w;
      // prefetch ax_r / ax_z for the NEXT step (consumed next phase 1)
      const int un = (u + 1 < NSTEP) ? u + 1 : u;
      const int ln = un >> 11, tn = un & (SEQ - 1);
      nax_r = *reinterpret_cast<const float4*>(
          &ax[(((size_t)ln * 3 + 0) * SEQ + tn) * HD + row0]);
      nax_z = *reinterpret_cast<const float4*>(
          &ax[(((size_t)ln * 3 + 1) * SEQ + tn) * HD + row0]);
    }
#pragma unroll
    for (int q = 0; q < 4; ++q) sVec[tid * 4 + q] = rv[q];
    __syncthreads();
    {
      const int task = tid >> 6;       // 0..3 (hh rows), 64 lanes each
      const int lane = tid & 63;
      const float* wrow = sW[l][2][task];
      float sum = 0.0f;
#pragma unroll 8
      for (int k = lane; k < HD; k += 64) sum += wrow[k] * sVec[k];
#pragma unroll
      for (int off = 32; off; off >>= 1) sum += __shfl_down(sum, off);
      if (lane == 0) {
        const float pre = sum + sAxH[task];
        const float hh = tanhf(pre);
        const float z = sZ[task];
        agstore(&hbuf[row0 + task], (1.0f - z) * sHold[task] + z * hh);
      }
    }
    gbarrier(++ph, wg, tid, flags, gen);
  }

  // (output, hidden) are identical: write h twice
  if (tid < RPW) {
    const float v = agload(&hbuf[row0 + tid]);
    outp[row0 + tid] = v;
    outp[HD + row0 + tid] = v;
  }
}

// ---------------------------------------------------------------------------
extern "C" void kernel_launch(void* const* d_in, const int* in_sizes, int n_in,
                              void* d_out, int out_size, void* d_ws, size_t ws_size,
                              hipStream_t stream) {
  const float* emb = (const float*)d_in[0];
  const float* Wr  = (const float*)d_in[1];
  const float* br  = (const float*)d_in[2];
  const float* Wz  = (const float*)d_in[3];
  const float* bz  = (const float*)d_in[4];
  const float* Wh  = (const float*)d_in[5];
  const float* bh  = (const float*)d_in[6];
  float* outp = (float*)d_out;

  float* ws    = (float*)d_ws;
  float* ax    = ws;                                  // 6*SEQ*HD fp32 = 50.3 MB
  float* hbuf  = ws + (size_t)6 * SEQ * HD;           // HD fp32
  float* rhbuf = hbuf + HD;                           // HD fp32
  int*   flags = (int*)(rhbuf + HD);                  // NWG ints
  int*   gen   = flags + NWG;                         // 1 int (+pad)

  // Deterministic barrier/hidden state each call (ws is NOT re-poisoned
  // between graph replays; phase counters must start from 0).
  hipMemsetAsync(hbuf, 0, (2 * HD + NWG + 64) * sizeof(float), stream);

  // Phase A: x-part contributions + bias, all gates/layers (parallel GEMM)
  dim3 g1(HD / 64, SEQ / 64, 6);
  ax_gemm_kernel<<<g1, 256, 0, stream>>>(emb, Wr, Wz, Wh, br, bz, bh, ax);

  // Phase B: serial scan; cooperative launch only for the co-residency
  // guarantee (custom barrier replaces grid.sync).
  void* args[] = {(void*)&Wr, (void*)&Wz, (void*)&Wh, (void*)&ax,
                  (void*)&hbuf, (void*)&rhbuf, (void*)&flags, (void*)&gen,
                  (void*)&outp};
  hipLaunchCooperativeKernel((const void*)gru_seq_kernel, dim3(NWG), dim3(TPB),
                             args, 0, stream);
}

// Round 3
// 28279.837 us; speedup vs baseline: 13.9403x; 10.2336x over previous
//
#include <hip/hip_runtime.h>
#include <hip/hip_cooperative_groups.h>

// Problem constants (B=2, S=1024, I=1024, H=1024, L=2)
constexpr int HD    = 1024;       // hidden size == input size
constexpr int SEQ   = 2048;       // B*S flattened steps per layer
constexpr int NL    = 2;          // layers
constexpr int NSTEP = NL * SEQ;   // 4096 serial steps
constexpr int NWG   = 256;        // workgroups (1 per CU)
constexpr int TPB   = 256;        // threads per block
constexpr int RPW   = HD / NWG;   // rows owned per WG = 4

// ---------------------------------------------------------------------------
// Device-coherent (cross-XCD) primitives with NO cache-maintenance ops.
// sc0 sc1 loads/stores bypass the non-coherent L1/L2 and hit the coherence
// point directly, so neither acquire-invalidate nor release-writeback is
// needed. Ordering comes from s_waitcnt + in-order wave execution.
// ---------------------------------------------------------------------------
__device__ __forceinline__ float4 agload4(const float* p) {
  float4 v;
  asm volatile("global_load_dwordx4 %0, %1, off sc0 sc1\n\t"
               "s_waitcnt vmcnt(0)"
               : "=v"(v) : "v"(p) : "memory");
  return v;
}
__device__ __forceinline__ void agstore(float* p, float v) {
  __hip_atomic_store(p, v, __ATOMIC_RELAXED, __HIP_MEMORY_SCOPE_AGENT);
}
__device__ __forceinline__ float agloadf(const float* p) {
  return __hip_atomic_load(p, __ATOMIC_RELAXED, __HIP_MEMORY_SCOPE_AGENT);
}
__device__ __forceinline__ int rload(const int* p) {
  return __hip_atomic_load(p, __ATOMIC_RELAXED, __HIP_MEMORY_SCOPE_AGENT);
}
__device__ __forceinline__ void rstore(int* p, int v) {
  __hip_atomic_store(p, v, __ATOMIC_RELAXED, __HIP_MEMORY_SCOPE_AGENT);
}

// ---------------------------------------------------------------------------
// Grid barrier, fence-free: per-WG flag (uncontended) + master-poll (WG0)
// + generation broadcast. Relaxed polls with s_sleep; release discipline is
// "each wave drains its own sc1 stores (vmcnt) before syncthreads".
// ---------------------------------------------------------------------------
__device__ __forceinline__ void gbarrier(int ph, int wg, int tid,
                                         int* flags, int* gen) {
  asm volatile("s_waitcnt vmcnt(0) lgkmcnt(0)" ::: "memory");  // drain own stores
  __syncthreads();                      // all waves of this WG done + drained
  if (tid == 0) rstore(&flags[wg], ph);
  if (wg == 0) {
    // 256 threads each poll one WG's flag — parallel detection, relaxed
    while (rload(&flags[tid]) < ph) __builtin_amdgcn_s_sleep(1);
    __syncthreads();
    if (tid == 0) rstore(gen, ph);
  }
  if (tid == 0) {
    while (rload(gen) < ph) __builtin_amdgcn_s_sleep(1);
  }
  __syncthreads();
}

// ---------------------------------------------------------------------------
// Phase A: Ax[gl][t][row] = X[t,:] . W_g[l][row, HD:2HD] + b_g[l][row]
// gl = l*3 + g, g in {0:r, 1:z, 2:h}. 64x64 fp32 LDS-tiled GEMM (unchanged).
// ---------------------------------------------------------------------------
__global__ void __launch_bounds__(256) ax_gemm_kernel(
    const float* __restrict__ X,
    const float* __restrict__ Wr, const float* __restrict__ Wz, const float* __restrict__ Wh,
    const float* __restrict__ br, const float* __restrict__ bz, const float* __restrict__ bh,
    float* __restrict__ ax)
{
  __shared__ float sX[16][64];   // [k][t]
  __shared__ float sW[16][64];   // [k][row]

  const int gl = blockIdx.z, l = gl / 3, g = gl % 3;
  const float* W    = (g == 0 ? Wr : (g == 1 ? Wz : Wh)) + (size_t)l * HD * (2 * HD) + HD;
  const float* bias = (g == 0 ? br : (g == 1 ? bz : bh)) + l * HD;
  const int t0 = blockIdx.y * 64, r0 = blockIdx.x * 64;
  const int tid = threadIdx.x;
  const int tx = tid & 15;        // row micro-tile index
  const int ty = tid >> 4;        // t  micro-tile index
  const int lt = tid >> 2;        // staging local row 0..63
  const int lk = (tid & 3) * 4;   // staging k offset {0,4,8,12}

  float acc[4][4] = {};           // [i: t][j: row]

  for (int k0 = 0; k0 < HD; k0 += 16) {
    float4 xv = *reinterpret_cast<const float4*>(&X[(size_t)(t0 + lt) * HD + k0 + lk]);
    float4 wv = *reinterpret_cast<const float4*>(&W[(size_t)(r0 + lt) * (2 * HD) + k0 + lk]);
    __syncthreads();
    sX[lk + 0][lt] = xv.x; sX[lk + 1][lt] = xv.y; sX[lk + 2][lt] = xv.z; sX[lk + 3][lt] = xv.w;
    sW[lk + 0][lt] = wv.x; sW[lk + 1][lt] = wv.y; sW[lk + 2][lt] = wv.z; sW[lk + 3][lt] = wv.w;
    __syncthreads();
#pragma unroll
    for (int k = 0; k < 16; ++k) {
      float4 a = *reinterpret_cast<const float4*>(&sX[k][ty * 4]);
      float4 b = *reinterpret_cast<const float4*>(&sW[k][tx * 4]);
      const float av[4] = {a.x, a.y, a.z, a.w};
      const float bv[4] = {b.x, b.y, b.z, b.w};
#pragma unroll
      for (int i = 0; i < 4; ++i)
#pragma unroll
        for (int j = 0; j < 4; ++j)
          acc[i][j] += av[i] * bv[j];
    }
  }

  float4 bb = *reinterpret_cast<const float4*>(&bias[r0 + tx * 4]);
  const float bv[4] = {bb.x, bb.y, bb.z, bb.w};
#pragma unroll
  for (int i = 0; i < 4; ++i) {
    float4 o;
    o.x = acc[i][0] + bv[0]; o.y = acc[i][1] + bv[1];
    o.z = acc[i][2] + bv[2]; o.w = acc[i][3] + bv[3];
    *reinterpret_cast<float4*>(
        &ax[((size_t)gl * SEQ + t0 + ty * 4 + i) * HD + r0 + tx * 4]) = o;
  }
}

// ---------------------------------------------------------------------------
// Phase B: 4096-step serial scan. WG b owns rows [4b,4b+4) of r/z/hh.
// h-part weights (96 KB fp32) in LDS. Two fence-free barriers per step;
// h / r*h exchanged via sc0sc1 dwordx4; ax prefetched one phase ahead.
// ---------------------------------------------------------------------------
__global__ void __launch_bounds__(TPB) gru_seq_kernel(
    const float* __restrict__ Wr, const float* __restrict__ Wz, const float* __restrict__ Wh,
    const float* __restrict__ ax,
    float* __restrict__ hbuf, float* __restrict__ rhbuf,
    int* __restrict__ flags, int* __restrict__ gen,
    float* __restrict__ outp)
{
  __shared__ float sW[NL][3][RPW][HD];  // 96 KB: h-part weight rows
  __shared__ float sVec[HD];            // staged h (phase 1) / r*h (phase 2)
  __shared__ float sAxRZ[2 * RPW];      // ax for r,z rows, current step
  __shared__ float sAxH[RPW];           // ax for hh rows, current step
  __shared__ float sZ[RPW];
  __shared__ float sHold[RPW];

  const int wg = blockIdx.x;
  const int tid = threadIdx.x;
  const int row0 = wg * RPW;

  // Stage weights once: h-part = columns [0, HD) of W_g[l][row]
  for (int f = tid; f < NL * 3 * RPW * HD; f += TPB) {
    const int k  = f & (HD - 1);
    const int rr = f >> 10;          // 0..23
    const int r  = rr & 3;
    const int g  = (rr >> 2) % 3;
    const int l  = (rr >> 2) / 3;
    const float* W = (g == 0 ? Wr : (g == 1 ? Wz : Wh));
    sW[l][g][r][k] = W[((size_t)l * HD + row0 + r) * (2 * HD) + k];
  }
  __syncthreads();

  // Prologue: prefetch ax_r / ax_z for step 0 (consumed in first phase 1)
  float4 nax_r, nax_z, axh;
  if (tid == 0) {
    nax_r = *reinterpret_cast<const float4*>(&ax[(size_t)0 * SEQ * HD + row0]);
    nax_z = *reinterpret_cast<const float4*>(&ax[(size_t)1 * SEQ * HD + row0]);
  }

  int ph = 0;
  for (int u = 0; u < NSTEP; ++u) {
    const int l = u >> 11;           // layer
    const int t = u & (SEQ - 1);     // step within layer

    // ---- phase 1: r, z rows; publish r*h -------------------------------
    float4 hv = agload4(&hbuf[tid * 4]);           // coherent h broadcast
    if (tid == 0) {
      // issue ax_h load for THIS step (consumed next phase — latency hidden)
      axh = *reinterpret_cast<const float4*>(
          &ax[(((size_t)l * 3 + 2) * SEQ + t) * HD + row0]);
      // publish the r/z ax values prefetched during the previous phase
      sAxRZ[0] = nax_r.x; sAxRZ[1] = nax_r.y; sAxRZ[2] = nax_r.z; sAxRZ[3] = nax_r.w;
      sAxRZ[4] = nax_z.x; sAxRZ[5] = nax_z.y; sAxRZ[6] = nax_z.z; sAxRZ[7] = nax_z.w;
    }
    *reinterpret_cast<float4*>(&sVec[tid * 4]) = hv;
    __syncthreads();
    {
      const int task = tid >> 5;       // 0..7 (0-3: r rows, 4-7: z rows)
      const int lane = tid & 31;
      const int g = task >> 2;         // 0=r, 1=z
      const int r = task & 3;
      const float* wrow = sW[l][g][r];
      float sum = 0.0f;
#pragma unroll 8
      for (int k = lane; k < HD; k += 32) sum += wrow[k] * sVec[k];
#pragma unroll
      for (int off = 16; off; off >>= 1) sum += __shfl_down(sum, off, 32);
      if (lane == 0) {
        const float pre = sum + sAxRZ[g * 4 + r];
        const float v = 1.0f / (1.0f + expf(-pre));
        if (g == 0) agstore(&rhbuf[row0 + r], v * sVec[row0 + r]);   // r*h
        else { sZ[r] = v; sHold[r] = sVec[row0 + r]; }               // z, old h
      }
    }
    gbarrier(++ph, wg, tid, flags, gen);

    // ---- phase 2: hh rows; local h update ------------------------------
    float4 rv = agload4(&rhbuf[tid * 4]);          // coherent r*h broadcast
    if (tid == 0) {
      sAxH[0] = axh.x; sAxH[1] = axh.y; sAxH[2] = axh.z; sAxH[3] = axh.w;
      // prefetch ax_r / ax_z for the NEXT step (consumed next phase 1)
      const int un = (u + 1 < NSTEP) ? u + 1 : u;
      const int ln = un >> 11, tn = un & (SEQ - 1);
      nax_r = *reinterpret_cast<const float4*>(
          &ax[(((size_t)ln * 3 + 0) * SEQ + tn) * HD + row0]);
      nax_z = *reinterpret_cast<const float4*>(
          &ax[(((size_t)ln * 3 + 1) * SEQ + tn) * HD + row0]);
    }
    *reinterpret_cast<float4*>(&sVec[tid * 4]) = rv;
    __syncthreads();
    {
      const int task = tid >> 6;       // 0..3 (hh rows), 64 lanes each
      const int lane = tid & 63;
      const float* wrow = sW[l][2][task];
      float sum = 0.0f;
#pragma unroll 8
      for (int k = lane; k < HD; k += 64) sum += wrow[k] * sVec[k];
#pragma unroll
      for (int off = 32; off; off >>= 1) sum += __shfl_down(sum, off);
      if (lane == 0) {
        const float pre = sum + sAxH[task];
        const float hh = tanhf(pre);
        const float z = sZ[task];
        agstore(&hbuf[row0 + task], (1.0f - z) * sHold[task] + z * hh);
      }
    }
    gbarrier(++ph, wg, tid, flags, gen);
  }

  // (output, hidden) are identical: write h twice
  if (tid < RPW) {
    const float v = agloadf(&hbuf[row0 + tid]);
    outp[row0 + tid] = v;
    outp[HD + row0 + tid] = v;
  }
}

// ---------------------------------------------------------------------------
extern "C" void kernel_launch(void* const* d_in, const int* in_sizes, int n_in,
                              void* d_out, int out_size, void* d_ws, size_t ws_size,
                              hipStream_t stream) {
  const float* emb = (const float*)d_in[0];
  const float* Wr  = (const float*)d_in[1];
  const float* br  = (const float*)d_in[2];
  const float* Wz  = (const float*)d_in[3];
  const float* bz  = (const float*)d_in[4];
  const float* Wh  = (const float*)d_in[5];
  const float* bh  = (const float*)d_in[6];
  float* outp = (float*)d_out;

  float* ws    = (float*)d_ws;
  float* ax    = ws;                                  // 6*SEQ*HD fp32 = 50.3 MB
  float* hbuf  = ws + (size_t)6 * SEQ * HD;           // HD fp32
  float* rhbuf = hbuf + HD;                           // HD fp32
  int*   flags = (int*)(rhbuf + HD);                  // NWG ints
  int*   gen   = flags + NWG;                         // 1 int (+pad)

  // Deterministic barrier/hidden state each call (ws is NOT re-poisoned
  // between graph replays; phase counters must start from 0).
  hipMemsetAsync(hbuf, 0, (2 * HD + NWG + 64) * sizeof(float), stream);

  // Phase A: x-part contributions + bias, all gates/layers (parallel GEMM)
  dim3 g1(HD / 64, SEQ / 64, 6);
  ax_gemm_kernel<<<g1, 256, 0, stream>>>(emb, Wr, Wz, Wh, br, bz, bh, ax);

  // Phase B: serial scan; cooperative launch only for the co-residency
  // guarantee (custom fence-free barrier replaces grid.sync).
  void* args[] = {(void*)&Wr, (void*)&Wz, (void*)&Wh, (void*)&ax,
                  (void*)&hbuf, (void*)&rhbuf, (void*)&flags, (void*)&gen,
                  (void*)&outp};
  hipLaunchCooperativeKernel((const void*)gru_seq_kernel, dim3(NWG), dim3(TPB),
                             args, 0, stream);
}

// Round 4
// 27892.477 us; speedup vs baseline: 14.1339x; 1.0139x over previous
//
#include <hip/hip_runtime.h>
#include <hip/hip_cooperative_groups.h>

// Problem constants (B=2, S=1024, I=1024, H=1024, L=2)
constexpr int HD    = 1024;       // hidden size == input size
constexpr int SEQ   = 2048;       // B*S flattened steps per layer
constexpr int NL    = 2;          // layers
constexpr int NSTEP = NL * SEQ;   // 4096 serial steps
constexpr int NWG   = 256;        // workgroups (1 per CU)
constexpr int TPB   = 256;        // threads per block
constexpr int RPW   = HD / NWG;   // rows owned per WG = 4

// ---------------------------------------------------------------------------
// Tagged-pair dataflow primitives. Pair = (f32 value, u32 tag) in 8 aligned
// bytes. The 8B atomic store is both the data AND the readiness signal:
// consumers poll the pair until tag == expected step. No barrier, no fence,
// no cache-maintenance ops anywhere (sc0 sc1 ops go straight to the
// coherence point; validated cross-XCD in rounds 3).
// ---------------------------------------------------------------------------
__device__ __forceinline__ void store_pair(float* base, int row, float v, int tag) {
  union { float2 f; unsigned long long u; } pk;
  pk.f.x = v; pk.f.y = __int_as_float(tag);
  __hip_atomic_store(reinterpret_cast<unsigned long long*>(base + 2 * row), pk.u,
                     __ATOMIC_RELAXED, __HIP_MEMORY_SCOPE_AGENT);
}

// Poll 4 pairs (32B) until all tags == tag; return the 4 values.
__device__ __forceinline__ float4 poll4(const float* p, int tag) {
  float2 a, b, c, d;
  while (true) {
    asm volatile(
        "global_load_dwordx2 %0, %4, off sc0 sc1\n\t"
        "global_load_dwordx2 %1, %4, off offset:8 sc0 sc1\n\t"
        "global_load_dwordx2 %2, %4, off offset:16 sc0 sc1\n\t"
        "global_load_dwordx2 %3, %4, off offset:24 sc0 sc1\n\t"
        "s_waitcnt vmcnt(0)"
        : "=&v"(a), "=&v"(b), "=&v"(c), "=&v"(d)
        : "v"(p)
        : "memory");
    if (__float_as_int(a.y) == tag && __float_as_int(b.y) == tag &&
        __float_as_int(c.y) == tag && __float_as_int(d.y) == tag)
      break;
  }
  float4 r; r.x = a.x; r.y = b.x; r.z = c.x; r.w = d.x;
  return r;
}

// ---------------------------------------------------------------------------
// Phase A: Ax[gl][t][row] = X[t,:] . W_g[l][row, HD:2HD] + b_g[l][row]
// gl = l*3 + g, g in {0:r, 1:z, 2:h}. 64x64 fp32 LDS-tiled GEMM (unchanged).
// ---------------------------------------------------------------------------
__global__ void __launch_bounds__(256) ax_gemm_kernel(
    const float* __restrict__ X,
    const float* __restrict__ Wr, const float* __restrict__ Wz, const float* __restrict__ Wh,
    const float* __restrict__ br, const float* __restrict__ bz, const float* __restrict__ bh,
    float* __restrict__ ax)
{
  __shared__ float sX[16][64];   // [k][t]
  __shared__ float sW[16][64];   // [k][row]

  const int gl = blockIdx.z, l = gl / 3, g = gl % 3;
  const float* W    = (g == 0 ? Wr : (g == 1 ? Wz : Wh)) + (size_t)l * HD * (2 * HD) + HD;
  const float* bias = (g == 0 ? br : (g == 1 ? bz : bh)) + l * HD;
  const int t0 = blockIdx.y * 64, r0 = blockIdx.x * 64;
  const int tid = threadIdx.x;
  const int tx = tid & 15;        // row micro-tile index
  const int ty = tid >> 4;        // t  micro-tile index
  const int lt = tid >> 2;        // staging local row 0..63
  const int lk = (tid & 3) * 4;   // staging k offset {0,4,8,12}

  float acc[4][4] = {};           // [i: t][j: row]

  for (int k0 = 0; k0 < HD; k0 += 16) {
    float4 xv = *reinterpret_cast<const float4*>(&X[(size_t)(t0 + lt) * HD + k0 + lk]);
    float4 wv = *reinterpret_cast<const float4*>(&W[(size_t)(r0 + lt) * (2 * HD) + k0 + lk]);
    __syncthreads();
    sX[lk + 0][lt] = xv.x; sX[lk + 1][lt] = xv.y; sX[lk + 2][lt] = xv.z; sX[lk + 3][lt] = xv.w;
    sW[lk + 0][lt] = wv.x; sW[lk + 1][lt] = wv.y; sW[lk + 2][lt] = wv.z; sW[lk + 3][lt] = wv.w;
    __syncthreads();
#pragma unroll
    for (int k = 0; k < 16; ++k) {
      float4 a = *reinterpret_cast<const float4*>(&sX[k][ty * 4]);
      float4 b = *reinterpret_cast<const float4*>(&sW[k][tx * 4]);
      const float av[4] = {a.x, a.y, a.z, a.w};
      const float bv[4] = {b.x, b.y, b.z, b.w};
#pragma unroll
      for (int i = 0; i < 4; ++i)
#pragma unroll
        for (int j = 0; j < 4; ++j)
          acc[i][j] += av[i] * bv[j];
    }
  }

  float4 bb = *reinterpret_cast<const float4*>(&bias[r0 + tx * 4]);
  const float bv[4] = {bb.x, bb.y, bb.z, bb.w};
#pragma unroll
  for (int i = 0; i < 4; ++i) {
    float4 o;
    o.x = acc[i][0] + bv[0]; o.y = acc[i][1] + bv[1];
    o.z = acc[i][2] + bv[2]; o.w = acc[i][3] + bv[3];
    *reinterpret_cast<float4*>(
        &ax[((size_t)gl * SEQ + t0 + ty * 4 + i) * HD + r0 + tx * 4]) = o;
  }
}

// ---------------------------------------------------------------------------
// Phase B: 4096-step serial scan, barrier-free tagged dataflow.
// WG b owns rows [4b,4b+4) of r/z/hh; h-part weights (96 KB fp32) in LDS.
// hpair / rhpair: [2 slots][1024 pairs], double-buffered by step parity.
//   h entering step u : slot u&1,     tag u    (memset 0 == step-0 init)
//   r*h of step u     : slot u&1,     tag u+1
//   h leaving step u  : slot (u+1)&1, tag u+1
// Overwrite safety: a producer reaching a write transitively proves every
// WG consumed the slot's previous generation (2 steps older). Tags are
// monotonic; equality-poll cannot be spoofed.
// ---------------------------------------------------------------------------
__global__ void __launch_bounds__(TPB) gru_seq_kernel(
    const float* __restrict__ Wr, const float* __restrict__ Wz, const float* __restrict__ Wh,
    const float* __restrict__ ax,
    float* __restrict__ hpair, float* __restrict__ rhpair,
    float* __restrict__ outp)
{
  __shared__ float sW[NL][3][RPW][HD];  // 96 KB: h-part weight rows
  __shared__ float sVec[HD];            // staged h (phase 1) / r*h (phase 2)
  __shared__ float sAxRZ[2 * RPW];      // ax for r,z rows, current step
  __shared__ float sAxH[RPW];           // ax for hh rows, current step
  __shared__ float sZ[RPW];
  __shared__ float sHold[RPW];

  const int wg = blockIdx.x;
  const int tid = threadIdx.x;
  const int row0 = wg * RPW;

  // Stage weights once: h-part = columns [0, HD) of W_g[l][row]
  for (int f = tid; f < NL * 3 * RPW * HD; f += TPB) {
    const int k  = f & (HD - 1);
    const int rr = f >> 10;          // 0..23
    const int r  = rr & 3;
    const int g  = (rr >> 2) % 3;
    const int l  = (rr >> 2) / 3;
    const float* W = (g == 0 ? Wr : (g == 1 ? Wz : Wh));
    sW[l][g][r][k] = W[((size_t)l * HD + row0 + r) * (2 * HD) + k];
  }
  __syncthreads();

  // Prologue: prefetch ax_r / ax_z for step 0 (consumed in first phase 1)
  float4 nax_r, nax_z, axh;
  if (tid == 0) {
    nax_r = *reinterpret_cast<const float4*>(&ax[(size_t)0 * SEQ * HD + row0]);
    nax_z = *reinterpret_cast<const float4*>(&ax[(size_t)1 * SEQ * HD + row0]);
  }

  for (int u = 0; u < NSTEP; ++u) {
    const int l = u >> 11;           // layer
    const int t = u & (SEQ - 1);     // step within layer
    const int slot = (u & 1) * 2 * HD;

    // ---- phase 1: r, z rows; publish tagged r*h -------------------------
    if (tid == 0) {
      // issue ax_h load for THIS step (consumed next phase — latency hidden)
      axh = *reinterpret_cast<const float4*>(
          &ax[(((size_t)l * 3 + 2) * SEQ + t) * HD + row0]);
      // publish the r/z ax values prefetched during the previous phase
      sAxRZ[0] = nax_r.x; sAxRZ[1] = nax_r.y; sAxRZ[2] = nax_r.z; sAxRZ[3] = nax_r.w;
      sAxRZ[4] = nax_z.x; sAxRZ[5] = nax_z.y; sAxRZ[6] = nax_z.z; sAxRZ[7] = nax_z.w;
    }
    float4 hv = poll4(&hpair[slot + 8 * tid], u);    // wait for h entering step u
    *reinterpret_cast<float4*>(&sVec[tid * 4]) = hv;
    __syncthreads();
    {
      const int task = tid >> 5;       // 0..7 (0-3: r rows, 4-7: z rows)
      const int lane = tid & 31;
      const int g = task >> 2;         // 0=r, 1=z
      const int r = task & 3;
      const float* wrow = sW[l][g][r];
      float sum = 0.0f;
#pragma unroll 8
      for (int k = lane; k < HD; k += 32) sum += wrow[k] * sVec[k];
#pragma unroll
      for (int off = 16; off; off >>= 1) sum += __shfl_down(sum, off, 32);
      if (lane == 0) {
        const float pre = sum + sAxRZ[g * 4 + r];
        const float v = 1.0f / (1.0f + expf(-pre));
        if (g == 0) store_pair(rhpair + slot, row0 + r, v * sVec[row0 + r], u + 1);
        else { sZ[r] = v; sHold[r] = sVec[row0 + r]; }   // z, old h
      }
    }
    __syncthreads();   // sVec reads done before phase-2 staging overwrites

    // ---- phase 2: hh rows; local h update; publish tagged h -------------
    if (tid == 0) {
      sAxH[0] = axh.x; sAxH[1] = axh.y; sAxH[2] = axh.z; sAxH[3] = axh.w;
      // prefetch ax_r / ax_z for the NEXT step (consumed next phase 1)
      const int un = (u + 1 < NSTEP) ? u + 1 : u;
      const int ln = un >> 11, tn = un & (SEQ - 1);
      nax_r = *reinterpret_cast<const float4*>(
          &ax[(((size_t)ln * 3 + 0) * SEQ + tn) * HD + row0]);
      nax_z = *reinterpret_cast<const float4*>(
          &ax[(((size_t)ln * 3 + 1) * SEQ + tn) * HD + row0]);
    }
    float4 rv = poll4(&rhpair[slot + 8 * tid], u + 1);   // wait for r*h of step u
    *reinterpret_cast<float4*>(&sVec[tid * 4]) = rv;
    __syncthreads();
    {
      const int task = tid >> 6;       // 0..3 (hh rows), 64 lanes each
      const int lane = tid & 63;
      const float* wrow = sW[l][2][task];
      float sum = 0.0f;
#pragma unroll 8
      for (int k = lane; k < HD; k += 64) sum += wrow[k] * sVec[k];
#pragma unroll
      for (int off = 32; off; off >>= 1) sum += __shfl_down(sum, off);
      if (lane == 0) {
        const float pre = sum + sAxH[task];
        const float hh = tanhf(pre);
        const float z = sZ[task];
        const float hn = (1.0f - z) * sHold[task] + z * hh;
        store_pair(hpair + ((u + 1) & 1) * 2 * HD, row0 + task, hn, u + 1);
        if (u == NSTEP - 1) {          // (output, hidden) identical
          outp[row0 + task] = hn;
          outp[HD + row0 + task] = hn;
        }
      }
    }
    __syncthreads();   // sVec/sZ/sHold reads done before next phase-1
  }
}

// ---------------------------------------------------------------------------
extern "C" void kernel_launch(void* const* d_in, const int* in_sizes, int n_in,
                              void* d_out, int out_size, void* d_ws, size_t ws_size,
                              hipStream_t stream) {
  const float* emb = (const float*)d_in[0];
  const float* Wr  = (const float*)d_in[1];
  const float* br  = (const float*)d_in[2];
  const float* Wz  = (const float*)d_in[3];
  const float* bz  = (const float*)d_in[4];
  const float* Wh  = (const float*)d_in[5];
  const float* bh  = (const float*)d_in[6];
  float* outp = (float*)d_out;

  float* ws     = (float*)d_ws;
  float* ax     = ws;                                 // 6*SEQ*HD fp32 = 50.3 MB
  float* hpair  = ws + (size_t)6 * SEQ * HD;          // 2 slots * 1024 pairs = 16 KB
  float* rhpair = hpair + 4 * HD;                     // 16 KB

  // Deterministic tag state each call: zero both parities of both pair
  // buffers (slot0 tag=0 == "h entering step 0", value 0.0).
  hipMemsetAsync(hpair, 0, 8 * HD * sizeof(float), stream);

  // Phase A: x-part contributions + bias, all gates/layers (parallel GEMM)
  dim3 g1(HD / 64, SEQ / 64, 6);
  ax_gemm_kernel<<<g1, 256, 0, stream>>>(emb, Wr, Wz, Wh, br, bz, bh, ax);

  // Phase B: serial scan; cooperative launch only for the co-residency
  // guarantee (tagged dataflow replaces all barriers).
  void* args[] = {(void*)&Wr, (void*)&Wz, (void*)&Wh, (void*)&ax,
                  (void*)&hpair, (void*)&rhpair, (void*)&outp};
  hipLaunchCooperativeKernel((const void*)gru_seq_kernel, dim3(NWG), dim3(TPB),
                             args, 0, stream);
}

// Round 5
// 27854.333 us; speedup vs baseline: 14.1533x; 1.0014x over previous
//
#include <hip/hip_runtime.h>
#include <hip/hip_cooperative_groups.h>

// Problem constants (B=2, S=1024, I=1024, H=1024, L=2)
constexpr int HD    = 1024;       // hidden size == input size
constexpr int SEQ   = 2048;       // B*S flattened steps per layer
constexpr int NL    = 2;          // layers
constexpr int NSTEP = NL * SEQ;   // 4096 serial steps
constexpr int NWG   = 256;        // workgroups (1 per CU)
constexpr int TPB   = 256;        // threads per block
constexpr int RPW   = HD / NWG;   // rows owned per WG = 4

typedef unsigned u32x4 __attribute__((ext_vector_type(4)));

// ---------------------------------------------------------------------------
// Packed-element dataflow: each exchanged element is 4 B = (u16 step-tag <<16
// | bf16 value). The store is both data AND readiness signal. A consumer
// thread polls its 4 contiguous elements with ONE dwordx4 (16 B) — 2x fewer
// poll bytes and 4x fewer poll instructions than round 4 (the congestion
// that was delaying the producers' stores). bf16 is used only inside dot
// products; the h-carry path stays fp32 in producer-local LDS.
// ---------------------------------------------------------------------------
__device__ __forceinline__ unsigned packbf(float v, unsigned tag) {
  unsigned b = __float_as_uint(v);
  b += 0x7FFFu + ((b >> 16) & 1u);          // RNE round to bf16
  return (tag << 16) | (b >> 16);
}
__device__ __forceinline__ float unpackbf(unsigned w) {
  return __uint_as_float(w << 16);
}
__device__ __forceinline__ void store_elem(unsigned* base, int row, unsigned w) {
  __hip_atomic_store(base + row, w, __ATOMIC_RELAXED, __HIP_MEMORY_SCOPE_AGENT);
}

// Poll 4 packed elements (16B, one load) until all tags == tag.
__device__ __forceinline__ u32x4 poll4(const unsigned* p, unsigned tag) {
  u32x4 v;
  while (true) {
    asm volatile("global_load_dwordx4 %0, %1, off sc0 sc1\n\t"
                 "s_waitcnt vmcnt(0)"
                 : "=v"(v) : "v"(p) : "memory");
    if ((v.x >> 16) == tag && (v.y >> 16) == tag &&
        (v.z >> 16) == tag && (v.w >> 16) == tag)
      break;
    __builtin_amdgcn_s_sleep(1);           // decongest the coherence point
  }
  return v;
}

// ---------------------------------------------------------------------------
// Phase A: Ax[gl][t][row] = X[t,:] . W_g[l][row, HD:2HD] + b_g[l][row]
// gl = l*3 + g, g in {0:r, 1:z, 2:h}. 64x64 fp32 LDS-tiled GEMM (unchanged).
// ---------------------------------------------------------------------------
__global__ void __launch_bounds__(256) ax_gemm_kernel(
    const float* __restrict__ X,
    const float* __restrict__ Wr, const float* __restrict__ Wz, const float* __restrict__ Wh,
    const float* __restrict__ br, const float* __restrict__ bz, const float* __restrict__ bh,
    float* __restrict__ ax)
{
  __shared__ float sX[16][64];   // [k][t]
  __shared__ float sW[16][64];   // [k][row]

  const int gl = blockIdx.z, l = gl / 3, g = gl % 3;
  const float* W    = (g == 0 ? Wr : (g == 1 ? Wz : Wh)) + (size_t)l * HD * (2 * HD) + HD;
  const float* bias = (g == 0 ? br : (g == 1 ? bz : bh)) + l * HD;
  const int t0 = blockIdx.y * 64, r0 = blockIdx.x * 64;
  const int tid = threadIdx.x;
  const int tx = tid & 15;        // row micro-tile index
  const int ty = tid >> 4;        // t  micro-tile index
  const int lt = tid >> 2;        // staging local row 0..63
  const int lk = (tid & 3) * 4;   // staging k offset {0,4,8,12}

  float acc[4][4] = {};           // [i: t][j: row]

  for (int k0 = 0; k0 < HD; k0 += 16) {
    float4 xv = *reinterpret_cast<const float4*>(&X[(size_t)(t0 + lt) * HD + k0 + lk]);
    float4 wv = *reinterpret_cast<const float4*>(&W[(size_t)(r0 + lt) * (2 * HD) + k0 + lk]);
    __syncthreads();
    sX[lk + 0][lt] = xv.x; sX[lk + 1][lt] = xv.y; sX[lk + 2][lt] = xv.z; sX[lk + 3][lt] = xv.w;
    sW[lk + 0][lt] = wv.x; sW[lk + 1][lt] = wv.y; sW[lk + 2][lt] = wv.z; sW[lk + 3][lt] = wv.w;
    __syncthreads();
#pragma unroll
    for (int k = 0; k < 16; ++k) {
      float4 a = *reinterpret_cast<const float4*>(&sX[k][ty * 4]);
      float4 b = *reinterpret_cast<const float4*>(&sW[k][tx * 4]);
      const float av[4] = {a.x, a.y, a.z, a.w};
      const float bv[4] = {b.x, b.y, b.z, b.w};
#pragma unroll
      for (int i = 0; i < 4; ++i)
#pragma unroll
        for (int j = 0; j < 4; ++j)
          acc[i][j] += av[i] * bv[j];
    }
  }

  float4 bb = *reinterpret_cast<const float4*>(&bias[r0 + tx * 4]);
  const float bv[4] = {bb.x, bb.y, bb.z, bb.w};
#pragma unroll
  for (int i = 0; i < 4; ++i) {
    float4 o;
    o.x = acc[i][0] + bv[0]; o.y = acc[i][1] + bv[1];
    o.z = acc[i][2] + bv[2]; o.w = acc[i][3] + bv[3];
    *reinterpret_cast<float4*>(
        &ax[((size_t)gl * SEQ + t0 + ty * 4 + i) * HD + r0 + tx * 4]) = o;
  }
}

// ---------------------------------------------------------------------------
// Phase B: 4096-step serial scan, barrier-free packed dataflow.
// hpack / rhpack: [2 slots][1024 u32], double-buffered by step parity.
//   h entering step u : slot u&1,     tag u    (memset 0 == step-0 init, h=0)
//   r*h of step u     : slot u&1,     tag u+1
//   h leaving step u  : slot (u+1)&1, tag u+1
// Overwrite safety: producer reaching a write transitively proves all WGs
// consumed the slot's previous generation (2 steps older); tags monotonic.
// ---------------------------------------------------------------------------
__global__ void __launch_bounds__(TPB) gru_seq_kernel(
    const float* __restrict__ Wr, const float* __restrict__ Wz, const float* __restrict__ Wh,
    const float* __restrict__ ax,
    unsigned* __restrict__ hpack, unsigned* __restrict__ rhpack,
    float* __restrict__ outp)
{
  __shared__ float sW[NL][3][RPW][HD];  // 96 KB: h-part weight rows (fp32)
  __shared__ float sVec[HD];            // staged h (phase 1) / r*h (phase 2)
  __shared__ float sHF32[RPW];          // OWN h rows, fp32 carry (never bf16)
  __shared__ float sAxRZ[2 * RPW];      // ax for r,z rows, current step
  __shared__ float sAxH[RPW];           // ax for hh rows, current step
  __shared__ float sZ[RPW];

  const int wg = blockIdx.x;
  const int tid = threadIdx.x;
  const int row0 = wg * RPW;

  // Stage weights once: h-part = columns [0, HD) of W_g[l][row]
  for (int f = tid; f < NL * 3 * RPW * HD; f += TPB) {
    const int k  = f & (HD - 1);
    const int rr = f >> 10;          // 0..23
    const int r  = rr & 3;
    const int g  = (rr >> 2) % 3;
    const int l  = (rr >> 2) / 3;
    const float* W = (g == 0 ? Wr : (g == 1 ? Wz : Wh));
    sW[l][g][r][k] = W[((size_t)l * HD + row0 + r) * (2 * HD) + k];
  }
  if (tid < RPW) sHF32[tid] = 0.0f;    // h0 = 0 (own rows, fp32)
  __syncthreads();

  // Prologue: prefetch ax_r / ax_z for step 0 (consumed in first phase 1)
  float4 nax_r, nax_z, axh;
  if (tid == 0) {
    nax_r = *reinterpret_cast<const float4*>(&ax[(size_t)0 * SEQ * HD + row0]);
    nax_z = *reinterpret_cast<const float4*>(&ax[(size_t)1 * SEQ * HD + row0]);
  }

  for (int u = 0; u < NSTEP; ++u) {
    const int l = u >> 11;           // layer
    const int t = u & (SEQ - 1);     // step within layer
    const int slot = (u & 1) * HD;

    // ---- phase 1: r, z rows; publish tagged r*h -------------------------
    if (tid == 0) {
      // issue ax_h load for THIS step (consumed next phase — latency hidden)
      axh = *reinterpret_cast<const float4*>(
          &ax[(((size_t)l * 3 + 2) * SEQ + t) * HD + row0]);
      // publish the r/z ax values prefetched during the previous phase
      sAxRZ[0] = nax_r.x; sAxRZ[1] = nax_r.y; sAxRZ[2] = nax_r.z; sAxRZ[3] = nax_r.w;
      sAxRZ[4] = nax_z.x; sAxRZ[5] = nax_z.y; sAxRZ[6] = nax_z.z; sAxRZ[7] = nax_z.w;
    }
    u32x4 hv = poll4(&hpack[slot + 4 * tid], (unsigned)u);  // h entering step u
    sVec[4 * tid + 0] = unpackbf(hv.x);
    sVec[4 * tid + 1] = unpackbf(hv.y);
    sVec[4 * tid + 2] = unpackbf(hv.z);
    sVec[4 * tid + 3] = unpackbf(hv.w);
    __syncthreads();
    {
      const int task = tid >> 5;       // 0..7 (0-3: r rows, 4-7: z rows)
      const int lane = tid & 31;
      const int g = task >> 2;         // 0=r, 1=z
      const int r = task & 3;
      const float* wrow = sW[l][g][r];
      float sum = 0.0f;
#pragma unroll 8
      for (int k = lane; k < HD; k += 32) sum += wrow[k] * sVec[k];
#pragma unroll
      for (int off = 16; off; off >>= 1) sum += __shfl_down(sum, off, 32);
      if (lane == 0) {
        const float pre = sum + sAxRZ[g * 4 + r];
        const float v = 1.0f / (1.0f + expf(-pre));
        if (g == 0)                     // r*h uses fp32 OWN h (carry path)
          store_elem(rhpack + slot, row0 + r, packbf(v * sHF32[r], (unsigned)(u + 1)));
        else sZ[r] = v;
      }
    }
    __syncthreads();   // sVec reads done before phase-2 staging overwrites

    // ---- phase 2: hh rows; local fp32 h update; publish tagged h --------
    if (tid == 0) {
      sAxH[0] = axh.x; sAxH[1] = axh.y; sAxH[2] = axh.z; sAxH[3] = axh.w;
      // prefetch ax_r / ax_z for the NEXT step (consumed next phase 1)
      const int un = (u + 1 < NSTEP) ? u + 1 : u;
      const int ln = un >> 11, tn = un & (SEQ - 1);
      nax_r = *reinterpret_cast<const float4*>(
          &ax[(((size_t)ln * 3 + 0) * SEQ + tn) * HD + row0]);
      nax_z = *reinterpret_cast<const float4*>(
          &ax[(((size_t)ln * 3 + 1) * SEQ + tn) * HD + row0]);
    }
    u32x4 rv = poll4(&rhpack[slot + 4 * tid], (unsigned)(u + 1)); // r*h of step u
    sVec[4 * tid + 0] = unpackbf(rv.x);
    sVec[4 * tid + 1] = unpackbf(rv.y);
    sVec[4 * tid + 2] = unpackbf(rv.z);
    sVec[4 * tid + 3] = unpackbf(rv.w);
    __syncthreads();
    {
      const int task = tid >> 6;       // 0..3 (hh rows), 64 lanes each
      const int lane = tid & 63;
      const float* wrow = sW[l][2][task];
      float sum = 0.0f;
#pragma unroll 8
      for (int k = lane; k < HD; k += 64) sum += wrow[k] * sVec[k];
#pragma unroll
      for (int off = 32; off; off >>= 1) sum += __shfl_down(sum, off);
      if (lane == 0) {
        const float pre = sum + sAxH[task];
        const float hh = tanhf(pre);
        const float z = sZ[task];
        const float hn = (1.0f - z) * sHF32[task] + z * hh;   // fp32 carry
        sHF32[task] = hn;
        store_elem(hpack + ((u + 1) & 1) * HD, row0 + task,
                   packbf(hn, (unsigned)(u + 1)));
        if (u == NSTEP - 1) {          // (output, hidden) identical
          outp[row0 + task] = hn;
          outp[HD + row0 + task] = hn;
        }
      }
    }
    __syncthreads();   // sVec/sZ/sHF32 reads done before next phase-1
  }
}

// ---------------------------------------------------------------------------
extern "C" void kernel_launch(void* const* d_in, const int* in_sizes, int n_in,
                              void* d_out, int out_size, void* d_ws, size_t ws_size,
                              hipStream_t stream) {
  const float* emb = (const float*)d_in[0];
  const float* Wr  = (const float*)d_in[1];
  const float* br  = (const float*)d_in[2];
  const float* Wz  = (const float*)d_in[3];
  const float* bz  = (const float*)d_in[4];
  const float* Wh  = (const float*)d_in[5];
  const float* bh  = (const float*)d_in[6];
  float* outp = (float*)d_out;

  float*    ws     = (float*)d_ws;
  float*    ax     = ws;                                // 6*SEQ*HD fp32 = 50.3 MB
  unsigned* hpack  = (unsigned*)(ws + (size_t)6 * SEQ * HD); // 2 slots * 1024 u32 = 8 KB
  unsigned* rhpack = hpack + 2 * HD;                    // 8 KB

  // Deterministic tag state each call: zero both parities of both pack
  // buffers (slot0 tag=0 == "h entering step 0", value bf16(0)).
  hipMemsetAsync(hpack, 0, 4 * HD * sizeof(unsigned), stream);

  // Phase A: x-part contributions + bias, all gates/layers (parallel GEMM)
  dim3 g1(HD / 64, SEQ / 64, 6);
  ax_gemm_kernel<<<g1, 256, 0, stream>>>(emb, Wr, Wz, Wh, br, bz, bh, ax);

  // Phase B: serial scan; cooperative launch only for the co-residency
  // guarantee (packed tagged dataflow replaces all barriers).
  void* args[] = {(void*)&Wr, (void*)&Wz, (void*)&Wh, (void*)&ax,
                  (void*)&hpack, (void*)&rhpack, (void*)&outp};
  hipLaunchCooperativeKernel((const void*)gru_seq_kernel, dim3(NWG), dim3(TPB),
                             args, 0, stream);
}

// Round 6
// 19842.865 us; speedup vs baseline: 19.8676x; 1.4037x over previous
//
#include <hip/hip_runtime.h>
#include <hip/hip_cooperative_groups.h>

// Problem constants (B=2, S=1024, I=1024, H=1024, L=2)
constexpr int HD    = 1024;       // hidden size == input size
constexpr int SEQ   = 2048;       // B*S flattened steps per layer
constexpr int NL    = 2;          // layers
constexpr int NSTEP = NL * SEQ;   // 4096 serial steps
constexpr int NWG   = 256;        // workgroups (1 per CU)
constexpr int TPB   = 256;        // threads per block
constexpr int RPW   = HD / NWG;   // rows owned per WG = 4
constexpr int NXCD  = 8;          // XCDs (mirror count)

typedef unsigned u32x4 __attribute__((ext_vector_type(4)));

// ---------------------------------------------------------------------------
// Packed-element dataflow with PER-XCD MIRRORS. Element = 4 B =
// (u16 step-tag <<16 | bf16 value); the store is both data and readiness
// signal. Round-5 result showed poll BYTES don't matter; the round-6 theory
// is per-LINE poll rate: one shared buffer line is polled by all 256 CUs,
// delaying the producer's store. Producers now multicast each element to 8
// mirrors (one per XCD, 4KB apart, all MALL-resident); each consumer polls
// only its own XCD's mirror -> 8x fewer readers hammering the written line.
// ---------------------------------------------------------------------------
__device__ __forceinline__ unsigned packbf(float v, unsigned tag) {
  unsigned b = __float_as_uint(v);
  b += 0x7FFFu + ((b >> 16) & 1u);          // RNE round to bf16
  return (tag << 16) | (b >> 16);
}
__device__ __forceinline__ float unpackbf(unsigned w) {
  return __uint_as_float(w << 16);
}
// Multicast one element to all 8 XCD mirrors (stride HD u32 = 4KB).
__device__ __forceinline__ void store_mcast(unsigned* base, unsigned w) {
#pragma unroll
  for (int m = 0; m < NXCD; ++m)
    __hip_atomic_store(base + m * HD, w, __ATOMIC_RELAXED, __HIP_MEMORY_SCOPE_AGENT);
}

// Poll 4 packed elements (16B, one load) until all tags == tag.
__device__ __forceinline__ u32x4 poll4(const unsigned* p, unsigned tag) {
  u32x4 v;
  while (true) {
    asm volatile("global_load_dwordx4 %0, %1, off sc0 sc1\n\t"
                 "s_waitcnt vmcnt(0)"
                 : "=v"(v) : "v"(p) : "memory");
    if ((v.x >> 16) == tag && (v.y >> 16) == tag &&
        (v.z >> 16) == tag && (v.w >> 16) == tag)
      break;
    __builtin_amdgcn_s_sleep(1);           // decongest the coherence point
  }
  return v;
}

// ---------------------------------------------------------------------------
// Phase A: Ax[gl][t][row] = X[t,:] . W_g[l][row, HD:2HD] + b_g[l][row]
// gl = l*3 + g, g in {0:r, 1:z, 2:h}. 64x64 fp32 LDS-tiled GEMM (unchanged).
// ---------------------------------------------------------------------------
__global__ void __launch_bounds__(256) ax_gemm_kernel(
    const float* __restrict__ X,
    const float* __restrict__ Wr, const float* __restrict__ Wz, const float* __restrict__ Wh,
    const float* __restrict__ br, const float* __restrict__ bz, const float* __restrict__ bh,
    float* __restrict__ ax)
{
  __shared__ float sX[16][64];   // [k][t]
  __shared__ float sW[16][64];   // [k][row]

  const int gl = blockIdx.z, l = gl / 3, g = gl % 3;
  const float* W    = (g == 0 ? Wr : (g == 1 ? Wz : Wh)) + (size_t)l * HD * (2 * HD) + HD;
  const float* bias = (g == 0 ? br : (g == 1 ? bz : bh)) + l * HD;
  const int t0 = blockIdx.y * 64, r0 = blockIdx.x * 64;
  const int tid = threadIdx.x;
  const int tx = tid & 15;        // row micro-tile index
  const int ty = tid >> 4;        // t  micro-tile index
  const int lt = tid >> 2;        // staging local row 0..63
  const int lk = (tid & 3) * 4;   // staging k offset {0,4,8,12}

  float acc[4][4] = {};           // [i: t][j: row]

  for (int k0 = 0; k0 < HD; k0 += 16) {
    float4 xv = *reinterpret_cast<const float4*>(&X[(size_t)(t0 + lt) * HD + k0 + lk]);
    float4 wv = *reinterpret_cast<const float4*>(&W[(size_t)(r0 + lt) * (2 * HD) + k0 + lk]);
    __syncthreads();
    sX[lk + 0][lt] = xv.x; sX[lk + 1][lt] = xv.y; sX[lk + 2][lt] = xv.z; sX[lk + 3][lt] = xv.w;
    sW[lk + 0][lt] = wv.x; sW[lk + 1][lt] = wv.y; sW[lk + 2][lt] = wv.z; sW[lk + 3][lt] = wv.w;
    __syncthreads();
#pragma unroll
    for (int k = 0; k < 16; ++k) {
      float4 a = *reinterpret_cast<const float4*>(&sX[k][ty * 4]);
      float4 b = *reinterpret_cast<const float4*>(&sW[k][tx * 4]);
      const float av[4] = {a.x, a.y, a.z, a.w};
      const float bv[4] = {b.x, b.y, b.z, b.w};
#pragma unroll
      for (int i = 0; i < 4; ++i)
#pragma unroll
        for (int j = 0; j < 4; ++j)
          acc[i][j] += av[i] * bv[j];
    }
  }

  float4 bb = *reinterpret_cast<const float4*>(&bias[r0 + tx * 4]);
  const float bv[4] = {bb.x, bb.y, bb.z, bb.w};
#pragma unroll
  for (int i = 0; i < 4; ++i) {
    float4 o;
    o.x = acc[i][0] + bv[0]; o.y = acc[i][1] + bv[1];
    o.z = acc[i][2] + bv[2]; o.w = acc[i][3] + bv[3];
    *reinterpret_cast<float4*>(
        &ax[((size_t)gl * SEQ + t0 + ty * 4 + i) * HD + r0 + tx * 4]) = o;
  }
}

// ---------------------------------------------------------------------------
// Phase B: 4096-step serial scan, barrier-free packed dataflow, 8x mirrored.
// hpack / rhpack layout: [2 slots][8 xcd-mirrors][1024 u32] (64 KB each).
//   h entering step u : slot u&1,     tag u    (memset 0 == step-0 init, h=0)
//   r*h of step u     : slot u&1,     tag u+1
//   h leaving step u  : slot (u+1)&1, tag u+1
// Overwrite safety: producer reaching a write transitively proves all WGs
// consumed the slot's previous generation (2 steps older); tags monotonic.
// ---------------------------------------------------------------------------
__global__ void __launch_bounds__(TPB) gru_seq_kernel(
    const float* __restrict__ Wr, const float* __restrict__ Wz, const float* __restrict__ Wh,
    const float* __restrict__ ax,
    unsigned* __restrict__ hpack, unsigned* __restrict__ rhpack,
    float* __restrict__ outp)
{
  __shared__ float sW[NL][3][RPW][HD];  // 96 KB: h-part weight rows (fp32)
  __shared__ float sVec[HD];            // staged h (phase 1) / r*h (phase 2)
  __shared__ float sHF32[RPW];          // OWN h rows, fp32 carry (never bf16)
  __shared__ float sAxRZ[2 * RPW];      // ax for r,z rows, current step
  __shared__ float sAxH[RPW];           // ax for hh rows, current step
  __shared__ float sZ[RPW];

  const int wg = blockIdx.x;
  const int tid = threadIdx.x;
  const int row0 = wg * RPW;

  // Which XCD is this WG on? (wave-uniform; HW-verified readable on gfx950)
  unsigned myxcd;
  asm("s_getreg_b32 %0, hwreg(HW_REG_XCC_ID)" : "=s"(myxcd));
  myxcd &= (NXCD - 1);

  // Stage weights once: h-part = columns [0, HD) of W_g[l][row]
  for (int f = tid; f < NL * 3 * RPW * HD; f += TPB) {
    const int k  = f & (HD - 1);
    const int rr = f >> 10;          // 0..23
    const int r  = rr & 3;
    const int g  = (rr >> 2) % 3;
    const int l  = (rr >> 2) / 3;
    const float* W = (g == 0 ? Wr : (g == 1 ? Wz : Wh));
    sW[l][g][r][k] = W[((size_t)l * HD + row0 + r) * (2 * HD) + k];
  }
  if (tid < RPW) sHF32[tid] = 0.0f;    // h0 = 0 (own rows, fp32)
  __syncthreads();

  // Prologue: prefetch ax_r / ax_z for step 0 (consumed in first phase 1)
  float4 nax_r, nax_z, axh;
  if (tid == 0) {
    nax_r = *reinterpret_cast<const float4*>(&ax[(size_t)0 * SEQ * HD + row0]);
    nax_z = *reinterpret_cast<const float4*>(&ax[(size_t)1 * SEQ * HD + row0]);
  }

  for (int u = 0; u < NSTEP; ++u) {
    const int l = u >> 11;           // layer
    const int t = u & (SEQ - 1);     // step within layer
    const int slot = (u & 1) * NXCD * HD;          // mirror-block base
    const int slotn = ((u + 1) & 1) * NXCD * HD;

    // ---- phase 1: r, z rows; publish tagged r*h -------------------------
    if (tid == 0) {
      // issue ax_h load for THIS step (consumed next phase — latency hidden)
      axh = *reinterpret_cast<const float4*>(
          &ax[(((size_t)l * 3 + 2) * SEQ + t) * HD + row0]);
      // publish the r/z ax values prefetched during the previous phase
      sAxRZ[0] = nax_r.x; sAxRZ[1] = nax_r.y; sAxRZ[2] = nax_r.z; sAxRZ[3] = nax_r.w;
      sAxRZ[4] = nax_z.x; sAxRZ[5] = nax_z.y; sAxRZ[6] = nax_z.z; sAxRZ[7] = nax_z.w;
    }
    u32x4 hv = poll4(&hpack[slot + myxcd * HD + 4 * tid], (unsigned)u);
    sVec[4 * tid + 0] = unpackbf(hv.x);
    sVec[4 * tid + 1] = unpackbf(hv.y);
    sVec[4 * tid + 2] = unpackbf(hv.z);
    sVec[4 * tid + 3] = unpackbf(hv.w);
    __syncthreads();
    {
      const int task = tid >> 5;       // 0..7 (0-3: r rows, 4-7: z rows)
      const int lane = tid & 31;
      const int g = task >> 2;         // 0=r, 1=z
      const int r = task & 3;
      const float* wrow = sW[l][g][r];
      float sum = 0.0f;
#pragma unroll 8
      for (int k = lane; k < HD; k += 32) sum += wrow[k] * sVec[k];
#pragma unroll
      for (int off = 16; off; off >>= 1) sum += __shfl_down(sum, off, 32);
      if (lane == 0) {
        const float pre = sum + sAxRZ[g * 4 + r];
        const float v = 1.0f / (1.0f + expf(-pre));
        if (g == 0)                     // r*h uses fp32 OWN h (carry path)
          store_mcast(rhpack + slot + row0 + r,
                      packbf(v * sHF32[r], (unsigned)(u + 1)));
        else sZ[r] = v;
      }
    }
    __syncthreads();   // sVec reads done before phase-2 staging overwrites

    // ---- phase 2: hh rows; local fp32 h update; publish tagged h --------
    if (tid == 0) {
      sAxH[0] = axh.x; sAxH[1] = axh.y; sAxH[2] = axh.z; sAxH[3] = axh.w;
      // prefetch ax_r / ax_z for the NEXT step (consumed next phase 1)
      const int un = (u + 1 < NSTEP) ? u + 1 : u;
      const int ln = un >> 11, tn = un & (SEQ - 1);
      nax_r = *reinterpret_cast<const float4*>(
          &ax[(((size_t)ln * 3 + 0) * SEQ + tn) * HD + row0]);
      nax_z = *reinterpret_cast<const float4*>(
          &ax[(((size_t)ln * 3 + 1) * SEQ + tn) * HD + row0]);
    }
    u32x4 rv = poll4(&rhpack[slot + myxcd * HD + 4 * tid], (unsigned)(u + 1));
    sVec[4 * tid + 0] = unpackbf(rv.x);
    sVec[4 * tid + 1] = unpackbf(rv.y);
    sVec[4 * tid + 2] = unpackbf(rv.z);
    sVec[4 * tid + 3] = unpackbf(rv.w);
    __syncthreads();
    {
      const int task = tid >> 6;       // 0..3 (hh rows), 64 lanes each
      const int lane = tid & 63;
      const float* wrow = sW[l][2][task];
      float sum = 0.0f;
#pragma unroll 8
      for (int k = lane; k < HD; k += 64) sum += wrow[k] * sVec[k];
#pragma unroll
      for (int off = 32; off; off >>= 1) sum += __shfl_down(sum, off);
      if (lane == 0) {
        const float pre = sum + sAxH[task];
        const float hh = tanhf(pre);
        const float z = sZ[task];
        const float hn = (1.0f - z) * sHF32[task] + z * hh;   // fp32 carry
        sHF32[task] = hn;
        store_mcast(hpack + slotn + row0 + task,
                    packbf(hn, (unsigned)(u + 1)));
        if (u == NSTEP - 1) {          // (output, hidden) identical
          outp[row0 + task] = hn;
          outp[HD + row0 + task] = hn;
        }
      }
    }
    __syncthreads();   // sVec/sZ/sHF32 reads done before next phase-1
  }
}

// ---------------------------------------------------------------------------
extern "C" void kernel_launch(void* const* d_in, const int* in_sizes, int n_in,
                              void* d_out, int out_size, void* d_ws, size_t ws_size,
                              hipStream_t stream) {
  const float* emb = (const float*)d_in[0];
  const float* Wr  = (const float*)d_in[1];
  const float* br  = (const float*)d_in[2];
  const float* Wz  = (const float*)d_in[3];
  const float* bz  = (const float*)d_in[4];
  const float* Wh  = (const float*)d_in[5];
  const float* bh  = (const float*)d_in[6];
  float* outp = (float*)d_out;

  float*    ws     = (float*)d_ws;
  float*    ax     = ws;                                // 6*SEQ*HD fp32 = 50.3 MB
  unsigned* hpack  = (unsigned*)(ws + (size_t)6 * SEQ * HD); // 2 slots*8 mirrors*1024 u32 = 64 KB
  unsigned* rhpack = hpack + 2 * NXCD * HD;             // 64 KB

  // Deterministic tag state each call: zero both parities of both mirrored
  // pack buffers (slot0 tag=0 == "h entering step 0", value bf16(0)).
  hipMemsetAsync(hpack, 0, 4 * NXCD * HD * sizeof(unsigned), stream);

  // Phase A: x-part contributions + bias, all gates/layers (parallel GEMM)
  dim3 g1(HD / 64, SEQ / 64, 6);
  ax_gemm_kernel<<<g1, 256, 0, stream>>>(emb, Wr, Wz, Wh, br, bz, bh, ax);

  // Phase B: serial scan; cooperative launch only for the co-residency
  // guarantee (mirrored tagged dataflow replaces all barriers).
  void* args[] = {(void*)&Wr, (void*)&Wz, (void*)&Wh, (void*)&ax,
                  (void*)&hpack, (void*)&rhpack, (void*)&outp};
  hipLaunchCooperativeKernel((const void*)gru_seq_kernel, dim3(NWG), dim3(TPB),
                             args, 0, stream);
}